// Round 12
// baseline (799.294 us; speedup 1.0000x reference)
//
#include <hip/hip_runtime.h>
#include <cstddef>
#include <cstdint>

// ---------------------------------------------------------------------------
// VAEAttentionBlock: GroupNorm(32) -> single-head attention (N=4096, d=512)
// -> out-proj + residual.  B=2, C=512, H=W=64.  Inputs f32, output f32.
// Round 12: (1) revert K=512 split-K (3% MfmaUtil); fuse q/k/v projections
// into ONE gemm (N=1536, grid 768 = 3/CU, A-tile 3x reuse) on the proven
// gemm_bt core.  (2) O-GEMM ksplit gets register prefetch-depth-1 (hides the
// ~900cy L3 latency of S reads exposed by vmcnt-before-ds_write) and a
// stride-66 padded f32 reduction (2-way banks = free).  Final = gemm_bt<3>.
// ---------------------------------------------------------------------------

typedef __attribute__((ext_vector_type(8))) short frag8;   // 8 bf16 in 4 VGPRs
typedef __attribute__((ext_vector_type(4))) float f32x4;   // MFMA accumulator

__device__ __forceinline__ float b2f(unsigned short u) {
    union { unsigned u32; float f; } v; v.u32 = ((unsigned)u) << 16; return v.f;
}
__device__ __forceinline__ unsigned short f2bu(float f) {
    unsigned u = __float_as_uint(f);
    unsigned r = u + 0x7fffu + ((u >> 16) & 1u);   // RNE
    return (unsigned short)(r >> 16);
}

// ---------------------------------------------------------------------------
__global__ __launch_bounds__(256) void cast_f32_bf16(const float* __restrict__ src,
                                                     unsigned short* __restrict__ dst,
                                                     int n) {
    int i = (blockIdx.x * 256 + threadIdx.x) * 8;
    if (i >= n) return;
    float4 a = *reinterpret_cast<const float4*>(src + i);
    float4 b = *reinterpret_cast<const float4*>(src + i + 4);
    float vv[8] = {a.x, a.y, a.z, a.w, b.x, b.y, b.z, b.w};
    union { unsigned short u16[8]; uint4 v; } o;
#pragma unroll
    for (int j = 0; j < 8; ++j) o.u16[j] = f2bu(vv[j]);
    *reinterpret_cast<uint4*>(dst + i) = o.v;
}

// ---------------------------------------------------------------------------
__global__ __launch_bounds__(256) void gn_stats(const float* __restrict__ x,
                                                float* __restrict__ stats) {
    const int tid = threadIdx.x;
    const float* p = x + (size_t)blockIdx.x * 65536;
    float s = 0.f, ss = 0.f;
    for (int i = tid * 8; i < 65536; i += 2048) {
        float4 a = *reinterpret_cast<const float4*>(p + i);
        float4 b = *reinterpret_cast<const float4*>(p + i + 4);
        float vv[8] = {a.x, a.y, a.z, a.w, b.x, b.y, b.z, b.w};
#pragma unroll
        for (int j = 0; j < 8; ++j) { s += vv[j]; ss += vv[j] * vv[j]; }
    }
#pragma unroll
    for (int o = 32; o; o >>= 1) { s += __shfl_xor(s, o, 64); ss += __shfl_xor(ss, o, 64); }
    __shared__ float rs[4], rss[4];
    int wv = tid >> 6, lane = tid & 63;
    if (lane == 0) { rs[wv] = s; rss[wv] = ss; }
    __syncthreads();
    if (tid == 0) {
        float S1 = rs[0] + rs[1] + rs[2] + rs[3];
        float S2 = rss[0] + rss[1] + rss[2] + rss[3];
        float mean = S1 * (1.f / 65536.f);
        float var  = fmaxf(S2 * (1.f / 65536.f) - mean * mean, 0.f);
        stats[blockIdx.x * 2 + 0] = mean;
        stats[blockIdx.x * 2 + 1] = rsqrtf(var + 1e-5f);
    }
}

// ---------------------------------------------------------------------------
__global__ __launch_bounds__(256) void build_t(const float* __restrict__ x,
                                               const float* __restrict__ stats,
                                               const float* __restrict__ gnw,
                                               const float* __restrict__ gnb,
                                               unsigned short* __restrict__ t) {
    __shared__ unsigned short tile[64 * 66];
    const int b = blockIdx.z, c0 = blockIdx.y * 64, hw0 = blockIdx.x * 64;
#pragma unroll
    for (int it = 0; it < 2; ++it) {
        int idx = it * 256 + threadIdx.x;
        int c = idx >> 3, v8 = idx & 7;
        int cg = c0 + c;
        int g = cg >> 4;
        float mean = stats[(b * 32 + g) * 2 + 0];
        float rstd = stats[(b * 32 + g) * 2 + 1];
        float sc = rstd * gnw[cg];
        float sh = gnb[cg] - mean * sc;
        const float* src = x + ((size_t)(b * 512 + cg)) * 4096 + hw0 + v8 * 8;
        float4 a = *reinterpret_cast<const float4*>(src);
        float4 bb = *reinterpret_cast<const float4*>(src + 4);
        float vv[8] = {a.x, a.y, a.z, a.w, bb.x, bb.y, bb.z, bb.w};
#pragma unroll
        for (int j = 0; j < 8; ++j)
            tile[c * 66 + v8 * 8 + j] = f2bu(vv[j] * sc + sh);
    }
    __syncthreads();
#pragma unroll
    for (int it = 0; it < 2; ++it) {
        int idx = it * 256 + threadIdx.x;
        int hw = idx >> 3, v8 = idx & 7;
        union { unsigned short u16[8]; uint4 v; } outv;
#pragma unroll
        for (int j = 0; j < 8; ++j) outv.u16[j] = tile[(v8 * 8 + j) * 66 + hw];
        *reinterpret_cast<uint4*>(t + ((size_t)(b * 4096 + hw0 + hw)) * 512 + c0 + v8 * 8) =
            outv.v;
    }
}

// ---------------------------------------------------------------------------
// Proven LDS-staged 128x128 GEMM core (as a device function body via macro-
// free duplication).  gemm_bt: MODE 2 (S) and MODE 3 (final, f32+residual).
// ---------------------------------------------------------------------------
template <int MODE>
__global__ __launch_bounds__(256) void gemm_bt(const unsigned short* __restrict__ A,
                                               const unsigned short* __restrict__ B,
                                               const unsigned short* __restrict__ bias,
                                               const float* __restrict__ resid,
                                               unsigned short* __restrict__ C,
                                               float* __restrict__ Cf,
                                               int M, int N, int K, float alpha) {
    __shared__ __attribute__((aligned(16))) unsigned short As[128 * 32];
    __shared__ __attribute__((aligned(16))) unsigned short Bs[128 * 32];

    const int tid = threadIdx.x;
    const int lane = tid & 63, wv = tid >> 6;
    const int lrow = lane & 15, quad = lane >> 4;
    const int wr = (wv & 1) * 64, wc = (wv >> 1) * 64;

    const unsigned short* Ag = A + ((size_t)blockIdx.x * 128 + wv * 16 + (lane >> 2)) * K + (lane & 3) * 8;
    const unsigned short* Bg = B + ((size_t)blockIdx.y * 128 + wv * 16 + (lane >> 2)) * K + (lane & 3) * 8;
    unsigned short* Aw = As + wv * 512 + (size_t)lane * 8;
    unsigned short* Bw = Bs + wv * 512 + (size_t)lane * 8;
    const size_t rowskip = (size_t)64 * K;

    f32x4 acc[4][4] = {};

    for (int k0 = 0; k0 < K; k0 += 32) {
        uint4 a0 = *reinterpret_cast<const uint4*>(Ag + k0);
        uint4 a1 = *reinterpret_cast<const uint4*>(Ag + k0 + rowskip);
        uint4 b0 = *reinterpret_cast<const uint4*>(Bg + k0);
        uint4 b1 = *reinterpret_cast<const uint4*>(Bg + k0 + rowskip);
        __syncthreads();
        *reinterpret_cast<uint4*>(Aw)        = a0;
        *reinterpret_cast<uint4*>(Aw + 2048) = a1;
        *reinterpret_cast<uint4*>(Bw)        = b0;
        *reinterpret_cast<uint4*>(Bw + 2048) = b1;
        __syncthreads();

        frag8 af[4], bf[4];
        const unsigned short* ap = As + (wr + lrow) * 32 + quad * 8;
        const unsigned short* bp = Bs + (wc + lrow) * 32 + quad * 8;
#pragma unroll
        for (int i = 0; i < 4; ++i) af[i] = *reinterpret_cast<const frag8*>(ap + i * 512);
#pragma unroll
        for (int j = 0; j < 4; ++j) bf[j] = *reinterpret_cast<const frag8*>(bp + j * 512);
#pragma unroll
        for (int i = 0; i < 4; ++i)
#pragma unroll
            for (int j = 0; j < 4; ++j)
                acc[i][j] = __builtin_amdgcn_mfma_f32_16x16x32_bf16(af[i], bf[j], acc[i][j], 0, 0, 0);
    }

    const int rowBase = blockIdx.x * 128 + wr + quad * 4;
    const int colBase = blockIdx.y * 128 + wc + lrow;
#pragma unroll
    for (int j = 0; j < 4; ++j) {
        const int col = colBase + j * 16;
        float badd = 0.f;
        if (MODE == 3 && bias) badd = b2f(bias[col]);
#pragma unroll
        for (int i = 0; i < 4; ++i) {
            const int row = rowBase + i * 16;
#pragma unroll
            for (int r = 0; r < 4; ++r) {
                const int rr = row + r;
                float v = acc[i][j][r];
                if (MODE == 2) v *= alpha;
                v += badd;
                if (MODE == 2) {
                    C[(size_t)rr * N + col] = f2bu(v);
                } else {   // MODE 3
                    size_t addr = ((size_t)(rr >> 12) * 512 + col) * 4096 + (rr & 4095);
                    Cf[addr] = v + resid[addr];
                }
            }
        }
    }
}

// ---------------------------------------------------------------------------
// Fused q/k/v projection: one 128x128-tile GEMM over N=1536 (weights for
// wq|wk|wv contiguous in ws).  grid (64, 12); blockIdx.y routes the epilogue:
// y 0-3 -> q, 4-7 -> k, 8-11 -> vT (transposed store).  K = 512.
// ---------------------------------------------------------------------------
__global__ __launch_bounds__(256) void gemm_qkv(const unsigned short* __restrict__ A,
                                                const unsigned short* __restrict__ Ball,
                                                const unsigned short* __restrict__ biasAll,
                                                unsigned short* __restrict__ q,
                                                unsigned short* __restrict__ k,
                                                unsigned short* __restrict__ vT) {
    __shared__ __attribute__((aligned(16))) unsigned short As[128 * 32];
    __shared__ __attribute__((aligned(16))) unsigned short Bs[128 * 32];
    const int K = 512;

    const int tid = threadIdx.x;
    const int lane = tid & 63, wv = tid >> 6;
    const int lrow = lane & 15, quad = lane >> 4;
    const int wr = (wv & 1) * 64, wc = (wv >> 1) * 64;

    const unsigned short* B = Ball + (size_t)blockIdx.y * 128 * 512;
    const unsigned short* Ag = A + ((size_t)blockIdx.x * 128 + wv * 16 + (lane >> 2)) * K + (lane & 3) * 8;
    const unsigned short* Bg = B + ((size_t)(wv * 16 + (lane >> 2))) * K + (lane & 3) * 8;
    unsigned short* Aw = As + wv * 512 + (size_t)lane * 8;
    unsigned short* Bw = Bs + wv * 512 + (size_t)lane * 8;
    const size_t rowskip = (size_t)64 * K;

    f32x4 acc[4][4] = {};

    for (int k0 = 0; k0 < K; k0 += 32) {
        uint4 a0 = *reinterpret_cast<const uint4*>(Ag + k0);
        uint4 a1 = *reinterpret_cast<const uint4*>(Ag + k0 + rowskip);
        uint4 b0 = *reinterpret_cast<const uint4*>(Bg + k0);
        uint4 b1 = *reinterpret_cast<const uint4*>(Bg + k0 + rowskip);
        __syncthreads();
        *reinterpret_cast<uint4*>(Aw)        = a0;
        *reinterpret_cast<uint4*>(Aw + 2048) = a1;
        *reinterpret_cast<uint4*>(Bw)        = b0;
        *reinterpret_cast<uint4*>(Bw + 2048) = b1;
        __syncthreads();

        frag8 af[4], bf[4];
        const unsigned short* ap = As + (wr + lrow) * 32 + quad * 8;
        const unsigned short* bp = Bs + (wc + lrow) * 32 + quad * 8;
#pragma unroll
        for (int i = 0; i < 4; ++i) af[i] = *reinterpret_cast<const frag8*>(ap + i * 512);
#pragma unroll
        for (int j = 0; j < 4; ++j) bf[j] = *reinterpret_cast<const frag8*>(bp + j * 512);
#pragma unroll
        for (int i = 0; i < 4; ++i)
#pragma unroll
            for (int j = 0; j < 4; ++j)
                acc[i][j] = __builtin_amdgcn_mfma_f32_16x16x32_bf16(af[i], bf[j], acc[i][j], 0, 0, 0);
    }

    const int rowBase = blockIdx.x * 128 + wr + quad * 4;
    const int colBase = wc + lrow;                       // 0..127 in-tile
    const int gbase = blockIdx.y * 128;                  // 0..1535
#pragma unroll
    for (int j = 0; j < 4; ++j) {
        const int colL = colBase + j * 16;
        const int gcol = gbase + colL;
        const float badd = b2f(biasAll[gcol]);
#pragma unroll
        for (int i = 0; i < 4; ++i) {
            const int row = rowBase + i * 16;
#pragma unroll
            for (int r = 0; r < 4; ++r) {
                const int rr = row + r;
                float v = acc[i][j][r] + badd;
                if (blockIdx.y < 4) {
                    q[(size_t)rr * 512 + gcol] = f2bu(v);
                } else if (blockIdx.y < 8) {
                    k[(size_t)rr * 512 + (gcol - 512)] = f2bu(v);
                } else {
                    int ch = gcol - 1024;
                    vT[((size_t)(rr >> 12) * 512 + ch) * 4096 + (rr & 4095)] = f2bu(v);
                }
            }
        }
    }
}

// ---------------------------------------------------------------------------
// O = P*V split-K GEMM (K=4096 only): 64x64 tile, 4 waves on K/4, wave-
// private LDS staging with register prefetch-depth-1, stride-66 padded f32
// reduction (2-way banks = free).  grid (M/64, N/64).
// ---------------------------------------------------------------------------
__global__ __launch_bounds__(256) void ksplit_o(const unsigned short* __restrict__ A,
                                                const unsigned short* __restrict__ B,
                                                unsigned short* __restrict__ C,
                                                int N, int K) {
    __shared__ __attribute__((aligned(16))) unsigned char smem[33792];
    const int tid = threadIdx.x;
    const int lane = tid & 63, wv = tid >> 6;
    const int lrow = lane & 15, quad = lane >> 4;
    const int Kw = K >> 2;

    unsigned short* Aw = (unsigned short*)smem + wv * 4096;        // 64x32
    unsigned short* Bw = Aw + 2048;                                // 64x32

    const unsigned short* Ag = A + ((size_t)blockIdx.x * 64 + (lane >> 2)) * K + wv * Kw + (lane & 3) * 8;
    const unsigned short* Bg = B + ((size_t)blockIdx.y * 64 + (lane >> 2)) * K + wv * Kw + (lane & 3) * 8;
    const size_t rs16 = (size_t)16 * K;

    f32x4 acc[4][4] = {};

    uint4 av[4], bv4[4];
#pragma unroll
    for (int i = 0; i < 4; ++i) {
        av[i]  = *reinterpret_cast<const uint4*>(Ag + i * rs16);
        bv4[i] = *reinterpret_cast<const uint4*>(Bg + i * rs16);
    }
    for (int k0 = 0; k0 < Kw; k0 += 32) {
#pragma unroll
        for (int i = 0; i < 4; ++i) {
            *reinterpret_cast<uint4*>(Aw + i * 512 + lane * 8) = av[i];
            *reinterpret_cast<uint4*>(Bw + i * 512 + lane * 8) = bv4[i];
        }
        const bool more = (k0 + 32) < Kw;
        uint4 na[4], nb[4];
        if (more) {
#pragma unroll
            for (int i = 0; i < 4; ++i) {
                na[i] = *reinterpret_cast<const uint4*>(Ag + k0 + 32 + i * rs16);
                nb[i] = *reinterpret_cast<const uint4*>(Bg + k0 + 32 + i * rs16);
            }
        }
        frag8 af[4], bf[4];
#pragma unroll
        for (int i = 0; i < 4; ++i) {
            af[i] = *reinterpret_cast<const frag8*>(Aw + i * 512 + lrow * 32 + quad * 8);
            bf[i] = *reinterpret_cast<const frag8*>(Bw + i * 512 + lrow * 32 + quad * 8);
        }
#pragma unroll
        for (int i = 0; i < 4; ++i)
#pragma unroll
            for (int j = 0; j < 4; ++j)
                acc[i][j] = __builtin_amdgcn_mfma_f32_16x16x32_bf16(af[i], bf[j], acc[i][j], 0, 0, 0);
        if (more) {
#pragma unroll
            for (int i = 0; i < 4; ++i) { av[i] = na[i]; bv4[i] = nb[i]; }
        }
    }

    __syncthreads();
    float* f0 = (float*)smem;            // 64 x 66 padded
    float* f1 = f0 + 4224;
    if (wv < 2) {
        float* fb = wv ? f1 : f0;
#pragma unroll
        for (int i = 0; i < 4; ++i)
#pragma unroll
            for (int j = 0; j < 4; ++j)
#pragma unroll
                for (int r = 0; r < 4; ++r)
                    fb[(i * 16 + quad * 4 + r) * 66 + j * 16 + lrow] = acc[i][j][r];
    }
    __syncthreads();
    if (wv >= 2) {
        float* fb = (wv == 3) ? f1 : f0;
#pragma unroll
        for (int i = 0; i < 4; ++i)
#pragma unroll
            for (int j = 0; j < 4; ++j)
#pragma unroll
                for (int r = 0; r < 4; ++r)
                    fb[(i * 16 + quad * 4 + r) * 66 + j * 16 + lrow] += acc[i][j][r];
    }
    __syncthreads();
#pragma unroll
    for (int e = 0; e < 16; ++e) {
        int idx = e * 256 + tid;
        int row = idx >> 6, col = idx & 63;
        C[((size_t)blockIdx.x * 64 + row) * N + blockIdx.y * 64 + col] =
            f2bu(f0[row * 66 + col] + f1[row * 66 + col]);
    }
}

// ---------------------------------------------------------------------------
__global__ __launch_bounds__(256) void softmax_rows(unsigned short* __restrict__ S) {
    __shared__ float red[8];
    const int tid = threadIdx.x;
    const int wv = tid >> 6, lane = tid & 63;
    unsigned short* p = S + (size_t)blockIdx.x * 4096 + tid * 16;

    uint4 r0 = *reinterpret_cast<const uint4*>(p);
    uint4 r1 = *reinterpret_cast<const uint4*>(p + 8);
    unsigned w[8] = {r0.x, r0.y, r0.z, r0.w, r1.x, r1.y, r1.z, r1.w};
    float v[16];
#pragma unroll
    for (int q2 = 0; q2 < 8; ++q2) {
        v[q2 * 2 + 0] = b2f((unsigned short)(w[q2] & 0xffffu));
        v[q2 * 2 + 1] = b2f((unsigned short)(w[q2] >> 16));
    }
    float m = -3.0e38f;
#pragma unroll
    for (int q2 = 0; q2 < 16; ++q2) m = fmaxf(m, v[q2]);
#pragma unroll
    for (int o = 32; o; o >>= 1) m = fmaxf(m, __shfl_xor(m, o, 64));
    if (lane == 0) red[wv] = m;
    __syncthreads();
    m = fmaxf(fmaxf(red[0], red[1]), fmaxf(red[2], red[3]));

    float s = 0.f;
#pragma unroll
    for (int q2 = 0; q2 < 16; ++q2) { v[q2] = __expf(v[q2] - m); s += v[q2]; }
#pragma unroll
    for (int o = 32; o; o >>= 1) s += __shfl_xor(s, o, 64);
    if (lane == 0) red[4 + wv] = s;
    __syncthreads();
    s = red[4] + red[5] + red[6] + red[7];
    const float inv = 1.f / s;

    unsigned ow[8];
#pragma unroll
    for (int q2 = 0; q2 < 8; ++q2) {
        unsigned lo = f2bu(v[q2 * 2 + 0] * inv);
        unsigned hi = f2bu(v[q2 * 2 + 1] * inv);
        ow[q2] = lo | (hi << 16);
    }
    uint4 o0 = {ow[0], ow[1], ow[2], ow[3]};
    uint4 o1 = {ow[4], ow[5], ow[6], ow[7]};
    *reinterpret_cast<uint4*>(p) = o0;
    *reinterpret_cast<uint4*>(p + 8) = o1;
}

__global__ void write_sentinel_f32(float* out, float code) {
    if (threadIdx.x == 0) out[0] = code;
}

// ---------------------------------------------------------------------------
extern "C" void kernel_launch(void* const* d_in, const int* in_sizes, int n_in,
                              void* d_out, int out_size, void* d_ws, size_t ws_size,
                              hipStream_t stream) {
    const float* x   = (const float*)d_in[0];
    const float* gnw = (const float*)d_in[1];
    const float* gnb = (const float*)d_in[2];
    const float* wq  = (const float*)d_in[3];
    const float* bq  = (const float*)d_in[4];
    const float* wk  = (const float*)d_in[5];
    const float* bk  = (const float*)d_in[6];
    const float* wv  = (const float*)d_in[7];
    const float* bv  = (const float*)d_in[8];
    const float* wo  = (const float*)d_in[9];
    const float* bo  = (const float*)d_in[10];
    float* out = (float*)d_out;

    bool shapes_ok = (n_in == 11 && in_sizes[0] == 4194304 && in_sizes[1] == 512 &&
                      in_sizes[3] == 262144 && out_size == 4194304);
    size_t half = ws_size / 2;
    if (!shapes_ok || half < (size_t)17831936 + 128 * 4096) {
        write_sentinel_f32<<<1, 64, 0, stream>>>(out, shapes_ok ? 8000.f : 9000.f);
        return;
    }

    unsigned short* ws = (unsigned short*)d_ws;
    unsigned short* t  = ws;
    unsigned short* q  = ws + 4194304;
    unsigned short* k  = ws + 8388608;
    unsigned short* vT = ws + 12582912;
    unsigned short* o  = t;                      // alias: t dead after qkv GEMM
    const float scale = 0.044194173824159216f;   // 512^-0.5

    // weight/bias bf16 copies: wq|wk|wv contiguous (gemm_qkv needs that).
    unsigned short* wB0 = ws + 16777216;         // 3 x 262144 contiguous
    unsigned short* wB3 = ws + 17563648;         // wo
    unsigned short* bB0 = ws + 17825792;         // 3 x 512 contiguous
    unsigned short* bB3 = ws + 17827328;         // bo
    float* stats = (float*)(ws + 17827840);

    cast_f32_bf16<<<128, 256, 0, stream>>>(wq, wB0,          262144);
    cast_f32_bf16<<<128, 256, 0, stream>>>(wk, wB0 + 262144, 262144);
    cast_f32_bf16<<<128, 256, 0, stream>>>(wv, wB0 + 524288, 262144);
    cast_f32_bf16<<<1, 256, 0, stream>>>(bq, bB0,        512);
    cast_f32_bf16<<<1, 256, 0, stream>>>(bk, bB0 + 512,  512);
    cast_f32_bf16<<<1, 256, 0, stream>>>(bv, bB0 + 1024, 512);

    gn_stats<<<64, 256, 0, stream>>>(x, stats);
    build_t<<<dim3(64, 8, 2), 256, 0, stream>>>(x, stats, gnw, gnb, t);
    gemm_qkv<<<dim3(64, 12), 256, 0, stream>>>(t, wB0, bB0, q, k, vT);

    if (half >= (size_t)33554432) {
        // full per-batch S aliased over the (now dead) wq/wk/wv copies
        unsigned short* S = ws + 16777216;
        for (int b = 0; b < 2; ++b) {
            const unsigned short* qb  = q  + (size_t)b * 2097152;
            const unsigned short* kb  = k  + (size_t)b * 2097152;
            const unsigned short* vTb = vT + (size_t)b * 2097152;
            unsigned short*       ob  = o  + (size_t)b * 2097152;
            gemm_bt<2><<<dim3(32, 32), 256, 0, stream>>>(qb, kb, nullptr, nullptr, S, nullptr,
                                                         4096, 4096, 512, scale);
            softmax_rows<<<4096, 256, 0, stream>>>(S);
            ksplit_o<<<dim3(64, 8), 256, 0, stream>>>(S, vTb, ob, 512, 4096);
        }
    } else {
        // chunked fallback (S after the weight copies)
        unsigned short* S = ws + 17831936;
        size_t avail = half - 17831936;
        int R = 4096;
        while (R > 128 && (size_t)R * 4096 > avail) R >>= 1;
        for (int b = 0; b < 2; ++b) {
            const unsigned short* qb  = q  + (size_t)b * 2097152;
            const unsigned short* kb  = k  + (size_t)b * 2097152;
            const unsigned short* vTb = vT + (size_t)b * 2097152;
            unsigned short*       ob  = o  + (size_t)b * 2097152;
            for (int r0 = 0; r0 < 4096; r0 += R) {
                gemm_bt<2><<<dim3(R / 128, 32), 256, 0, stream>>>(
                    qb + (size_t)r0 * 512, kb, nullptr, nullptr, S, nullptr, R, 4096, 512, scale);
                softmax_rows<<<R, 256, 0, stream>>>(S);
                ksplit_o<<<dim3(R / 64, 8), 256, 0, stream>>>(
                    S, vTb, ob + (size_t)r0 * 512, 512, 4096);
            }
        }
    }
    // final projection (wo/bo cast after S is dead; region inside S span)
    cast_f32_bf16<<<128, 256, 0, stream>>>(wo, wB3, 262144);
    cast_f32_bf16<<<1, 256, 0, stream>>>(bo, bB3, 512);
    gemm_bt<3><<<dim3(64, 4), 256, 0, stream>>>(o, wB3, bB3, x, nullptr, out,
                                                8192, 512, 512, 1.f);
}

// Round 13
// 326.697 us; speedup vs baseline: 2.4466x; 2.4466x over previous
//
#include <hip/hip_runtime.h>
#include <cstddef>
#include <cstdint>

// ---------------------------------------------------------------------------
// VAEAttentionBlock: GroupNorm(32) -> single-head attention (N=4096, d=512)
// -> out-proj + residual.  B=2, C=512, H=W=64.  Inputs f32, output f32.
// Round 13: revert round-12's ksplit_o register-prefetch (it SPILLED: 1 GB
// scratch writes/dispatch, 290 us).  ksplit_o is back to the byte-exact
// round-9 structure (43 us proven).  Keep the q/k/v fused projection
// (one N=1536 GEMM, grid 768 = 3/CU, A-tile 3x reuse).
// ---------------------------------------------------------------------------

typedef __attribute__((ext_vector_type(8))) short frag8;   // 8 bf16 in 4 VGPRs
typedef __attribute__((ext_vector_type(4))) float f32x4;   // MFMA accumulator

__device__ __forceinline__ float b2f(unsigned short u) {
    union { unsigned u32; float f; } v; v.u32 = ((unsigned)u) << 16; return v.f;
}
__device__ __forceinline__ unsigned short f2bu(float f) {
    unsigned u = __float_as_uint(f);
    unsigned r = u + 0x7fffu + ((u >> 16) & 1u);   // RNE
    return (unsigned short)(r >> 16);
}

// ---------------------------------------------------------------------------
__global__ __launch_bounds__(256) void cast_f32_bf16(const float* __restrict__ src,
                                                     unsigned short* __restrict__ dst,
                                                     int n) {
    int i = (blockIdx.x * 256 + threadIdx.x) * 8;
    if (i >= n) return;
    float4 a = *reinterpret_cast<const float4*>(src + i);
    float4 b = *reinterpret_cast<const float4*>(src + i + 4);
    float vv[8] = {a.x, a.y, a.z, a.w, b.x, b.y, b.z, b.w};
    union { unsigned short u16[8]; uint4 v; } o;
#pragma unroll
    for (int j = 0; j < 8; ++j) o.u16[j] = f2bu(vv[j]);
    *reinterpret_cast<uint4*>(dst + i) = o.v;
}

// ---------------------------------------------------------------------------
__global__ __launch_bounds__(256) void gn_stats(const float* __restrict__ x,
                                                float* __restrict__ stats) {
    const int tid = threadIdx.x;
    const float* p = x + (size_t)blockIdx.x * 65536;
    float s = 0.f, ss = 0.f;
    for (int i = tid * 8; i < 65536; i += 2048) {
        float4 a = *reinterpret_cast<const float4*>(p + i);
        float4 b = *reinterpret_cast<const float4*>(p + i + 4);
        float vv[8] = {a.x, a.y, a.z, a.w, b.x, b.y, b.z, b.w};
#pragma unroll
        for (int j = 0; j < 8; ++j) { s += vv[j]; ss += vv[j] * vv[j]; }
    }
#pragma unroll
    for (int o = 32; o; o >>= 1) { s += __shfl_xor(s, o, 64); ss += __shfl_xor(ss, o, 64); }
    __shared__ float rs[4], rss[4];
    int wv = tid >> 6, lane = tid & 63;
    if (lane == 0) { rs[wv] = s; rss[wv] = ss; }
    __syncthreads();
    if (tid == 0) {
        float S1 = rs[0] + rs[1] + rs[2] + rs[3];
        float S2 = rss[0] + rss[1] + rss[2] + rss[3];
        float mean = S1 * (1.f / 65536.f);
        float var  = fmaxf(S2 * (1.f / 65536.f) - mean * mean, 0.f);
        stats[blockIdx.x * 2 + 0] = mean;
        stats[blockIdx.x * 2 + 1] = rsqrtf(var + 1e-5f);
    }
}

// ---------------------------------------------------------------------------
__global__ __launch_bounds__(256) void build_t(const float* __restrict__ x,
                                               const float* __restrict__ stats,
                                               const float* __restrict__ gnw,
                                               const float* __restrict__ gnb,
                                               unsigned short* __restrict__ t) {
    __shared__ unsigned short tile[64 * 66];
    const int b = blockIdx.z, c0 = blockIdx.y * 64, hw0 = blockIdx.x * 64;
#pragma unroll
    for (int it = 0; it < 2; ++it) {
        int idx = it * 256 + threadIdx.x;
        int c = idx >> 3, v8 = idx & 7;
        int cg = c0 + c;
        int g = cg >> 4;
        float mean = stats[(b * 32 + g) * 2 + 0];
        float rstd = stats[(b * 32 + g) * 2 + 1];
        float sc = rstd * gnw[cg];
        float sh = gnb[cg] - mean * sc;
        const float* src = x + ((size_t)(b * 512 + cg)) * 4096 + hw0 + v8 * 8;
        float4 a = *reinterpret_cast<const float4*>(src);
        float4 bb = *reinterpret_cast<const float4*>(src + 4);
        float vv[8] = {a.x, a.y, a.z, a.w, bb.x, bb.y, bb.z, bb.w};
#pragma unroll
        for (int j = 0; j < 8; ++j)
            tile[c * 66 + v8 * 8 + j] = f2bu(vv[j] * sc + sh);
    }
    __syncthreads();
#pragma unroll
    for (int it = 0; it < 2; ++it) {
        int idx = it * 256 + threadIdx.x;
        int hw = idx >> 3, v8 = idx & 7;
        union { unsigned short u16[8]; uint4 v; } outv;
#pragma unroll
        for (int j = 0; j < 8; ++j) outv.u16[j] = tile[(v8 * 8 + j) * 66 + hw];
        *reinterpret_cast<uint4*>(t + ((size_t)(b * 4096 + hw0 + hw)) * 512 + c0 + v8 * 8) =
            outv.v;
    }
}

// ---------------------------------------------------------------------------
// Proven LDS-staged 128x128 GEMM.  MODE 2 (S) and MODE 3 (final f32+resid).
// ---------------------------------------------------------------------------
template <int MODE>
__global__ __launch_bounds__(256) void gemm_bt(const unsigned short* __restrict__ A,
                                               const unsigned short* __restrict__ B,
                                               const unsigned short* __restrict__ bias,
                                               const float* __restrict__ resid,
                                               unsigned short* __restrict__ C,
                                               float* __restrict__ Cf,
                                               int M, int N, int K, float alpha) {
    __shared__ __attribute__((aligned(16))) unsigned short As[128 * 32];
    __shared__ __attribute__((aligned(16))) unsigned short Bs[128 * 32];

    const int tid = threadIdx.x;
    const int lane = tid & 63, wv = tid >> 6;
    const int lrow = lane & 15, quad = lane >> 4;
    const int wr = (wv & 1) * 64, wc = (wv >> 1) * 64;

    const unsigned short* Ag = A + ((size_t)blockIdx.x * 128 + wv * 16 + (lane >> 2)) * K + (lane & 3) * 8;
    const unsigned short* Bg = B + ((size_t)blockIdx.y * 128 + wv * 16 + (lane >> 2)) * K + (lane & 3) * 8;
    unsigned short* Aw = As + wv * 512 + (size_t)lane * 8;
    unsigned short* Bw = Bs + wv * 512 + (size_t)lane * 8;
    const size_t rowskip = (size_t)64 * K;

    f32x4 acc[4][4] = {};

    for (int k0 = 0; k0 < K; k0 += 32) {
        uint4 a0 = *reinterpret_cast<const uint4*>(Ag + k0);
        uint4 a1 = *reinterpret_cast<const uint4*>(Ag + k0 + rowskip);
        uint4 b0 = *reinterpret_cast<const uint4*>(Bg + k0);
        uint4 b1 = *reinterpret_cast<const uint4*>(Bg + k0 + rowskip);
        __syncthreads();
        *reinterpret_cast<uint4*>(Aw)        = a0;
        *reinterpret_cast<uint4*>(Aw + 2048) = a1;
        *reinterpret_cast<uint4*>(Bw)        = b0;
        *reinterpret_cast<uint4*>(Bw + 2048) = b1;
        __syncthreads();

        frag8 af[4], bf[4];
        const unsigned short* ap = As + (wr + lrow) * 32 + quad * 8;
        const unsigned short* bp = Bs + (wc + lrow) * 32 + quad * 8;
#pragma unroll
        for (int i = 0; i < 4; ++i) af[i] = *reinterpret_cast<const frag8*>(ap + i * 512);
#pragma unroll
        for (int j = 0; j < 4; ++j) bf[j] = *reinterpret_cast<const frag8*>(bp + j * 512);
#pragma unroll
        for (int i = 0; i < 4; ++i)
#pragma unroll
            for (int j = 0; j < 4; ++j)
                acc[i][j] = __builtin_amdgcn_mfma_f32_16x16x32_bf16(af[i], bf[j], acc[i][j], 0, 0, 0);
    }

    const int rowBase = blockIdx.x * 128 + wr + quad * 4;
    const int colBase = blockIdx.y * 128 + wc + lrow;
#pragma unroll
    for (int j = 0; j < 4; ++j) {
        const int col = colBase + j * 16;
        float badd = 0.f;
        if (MODE == 3 && bias) badd = b2f(bias[col]);
#pragma unroll
        for (int i = 0; i < 4; ++i) {
            const int row = rowBase + i * 16;
#pragma unroll
            for (int r = 0; r < 4; ++r) {
                const int rr = row + r;
                float v = acc[i][j][r];
                if (MODE == 2) v *= alpha;
                v += badd;
                if (MODE == 2) {
                    C[(size_t)rr * N + col] = f2bu(v);
                } else {   // MODE 3
                    size_t addr = ((size_t)(rr >> 12) * 512 + col) * 4096 + (rr & 4095);
                    Cf[addr] = v + resid[addr];
                }
            }
        }
    }
}

// ---------------------------------------------------------------------------
// Fused q/k/v projection: one 128x128-tile GEMM over N=1536.  grid (64,12);
// blockIdx.y routes the epilogue: 0-3 -> q, 4-7 -> k, 8-11 -> vT.
// ---------------------------------------------------------------------------
__global__ __launch_bounds__(256) void gemm_qkv(const unsigned short* __restrict__ A,
                                                const unsigned short* __restrict__ Ball,
                                                const unsigned short* __restrict__ biasAll,
                                                unsigned short* __restrict__ q,
                                                unsigned short* __restrict__ k,
                                                unsigned short* __restrict__ vT) {
    __shared__ __attribute__((aligned(16))) unsigned short As[128 * 32];
    __shared__ __attribute__((aligned(16))) unsigned short Bs[128 * 32];
    const int K = 512;

    const int tid = threadIdx.x;
    const int lane = tid & 63, wv = tid >> 6;
    const int lrow = lane & 15, quad = lane >> 4;
    const int wr = (wv & 1) * 64, wc = (wv >> 1) * 64;

    const unsigned short* B = Ball + (size_t)blockIdx.y * 128 * 512;
    const unsigned short* Ag = A + ((size_t)blockIdx.x * 128 + wv * 16 + (lane >> 2)) * K + (lane & 3) * 8;
    const unsigned short* Bg = B + ((size_t)(wv * 16 + (lane >> 2))) * K + (lane & 3) * 8;
    unsigned short* Aw = As + wv * 512 + (size_t)lane * 8;
    unsigned short* Bw = Bs + wv * 512 + (size_t)lane * 8;
    const size_t rowskip = (size_t)64 * K;

    f32x4 acc[4][4] = {};

    for (int k0 = 0; k0 < K; k0 += 32) {
        uint4 a0 = *reinterpret_cast<const uint4*>(Ag + k0);
        uint4 a1 = *reinterpret_cast<const uint4*>(Ag + k0 + rowskip);
        uint4 b0 = *reinterpret_cast<const uint4*>(Bg + k0);
        uint4 b1 = *reinterpret_cast<const uint4*>(Bg + k0 + rowskip);
        __syncthreads();
        *reinterpret_cast<uint4*>(Aw)        = a0;
        *reinterpret_cast<uint4*>(Aw + 2048) = a1;
        *reinterpret_cast<uint4*>(Bw)        = b0;
        *reinterpret_cast<uint4*>(Bw + 2048) = b1;
        __syncthreads();

        frag8 af[4], bf[4];
        const unsigned short* ap = As + (wr + lrow) * 32 + quad * 8;
        const unsigned short* bp = Bs + (wc + lrow) * 32 + quad * 8;
#pragma unroll
        for (int i = 0; i < 4; ++i) af[i] = *reinterpret_cast<const frag8*>(ap + i * 512);
#pragma unroll
        for (int j = 0; j < 4; ++j) bf[j] = *reinterpret_cast<const frag8*>(bp + j * 512);
#pragma unroll
        for (int i = 0; i < 4; ++i)
#pragma unroll
            for (int j = 0; j < 4; ++j)
                acc[i][j] = __builtin_amdgcn_mfma_f32_16x16x32_bf16(af[i], bf[j], acc[i][j], 0, 0, 0);
    }

    const int rowBase = blockIdx.x * 128 + wr + quad * 4;
    const int colBase = wc + lrow;
    const int gbase = blockIdx.y * 128;
#pragma unroll
    for (int j = 0; j < 4; ++j) {
        const int colL = colBase + j * 16;
        const int gcol = gbase + colL;
        const float badd = b2f(biasAll[gcol]);
#pragma unroll
        for (int i = 0; i < 4; ++i) {
            const int row = rowBase + i * 16;
#pragma unroll
            for (int r = 0; r < 4; ++r) {
                const int rr = row + r;
                float v = acc[i][j][r] + badd;
                if (blockIdx.y < 4) {
                    q[(size_t)rr * 512 + gcol] = f2bu(v);
                } else if (blockIdx.y < 8) {
                    k[(size_t)rr * 512 + (gcol - 512)] = f2bu(v);
                } else {
                    int ch = gcol - 1024;
                    vT[((size_t)(rr >> 12) * 512 + ch) * 4096 + (rr & 4095)] = f2bu(v);
                }
            }
        }
    }
}

// ---------------------------------------------------------------------------
// O = P*V split-K GEMM — byte-exact round-9 structure (43 us proven):
// 64x64 tile, 4 waves each on K/4 with wave-private register->LDS staging
// (no prefetch, no K-loop barriers), 2-stage LDS f32 reduction.
// ---------------------------------------------------------------------------
__global__ __launch_bounds__(256) void ksplit_o(const unsigned short* __restrict__ A,
                                                const unsigned short* __restrict__ B,
                                                unsigned short* __restrict__ C,
                                                int N, int K) {
    __shared__ __attribute__((aligned(16))) unsigned char smem[32768];
    const int tid = threadIdx.x;
    const int lane = tid & 63, wv = tid >> 6;
    const int lrow = lane & 15, quad = lane >> 4;
    const int Kw = K >> 2;

    unsigned short* Aw = (unsigned short*)smem + wv * 4096;        // 64x32
    unsigned short* Bw = Aw + 2048;                                // 64x32

    const unsigned short* Ag = A + ((size_t)blockIdx.x * 64 + (lane >> 2)) * K + wv * Kw + (lane & 3) * 8;
    const unsigned short* Bg = B + ((size_t)blockIdx.y * 64 + (lane >> 2)) * K + wv * Kw + (lane & 3) * 8;
    const size_t rowskip16 = (size_t)16 * K;

    f32x4 acc[4][4] = {};

    for (int k0 = 0; k0 < Kw; k0 += 32) {
        uint4 av[4], bv_[4];
#pragma unroll
        for (int i = 0; i < 4; ++i) {
            av[i]  = *reinterpret_cast<const uint4*>(Ag + k0 + i * rowskip16);
            bv_[i] = *reinterpret_cast<const uint4*>(Bg + k0 + i * rowskip16);
        }
#pragma unroll
        for (int i = 0; i < 4; ++i) {
            *reinterpret_cast<uint4*>(Aw + i * 512 + lane * 8) = av[i];
            *reinterpret_cast<uint4*>(Bw + i * 512 + lane * 8) = bv_[i];
        }
        frag8 af[4], bf[4];
#pragma unroll
        for (int i = 0; i < 4; ++i) {
            af[i] = *reinterpret_cast<const frag8*>(Aw + i * 512 + lrow * 32 + quad * 8);
            bf[i] = *reinterpret_cast<const frag8*>(Bw + i * 512 + lrow * 32 + quad * 8);
        }
#pragma unroll
        for (int i = 0; i < 4; ++i)
#pragma unroll
            for (int j = 0; j < 4; ++j)
                acc[i][j] = __builtin_amdgcn_mfma_f32_16x16x32_bf16(af[i], bf[j], acc[i][j], 0, 0, 0);
    }

    __syncthreads();
    float* f0 = (float*)smem;           // 4096 f32
    float* f1 = f0 + 4096;              // 4096 f32
    if (wv < 2) {
        float* fb = wv ? f1 : f0;
#pragma unroll
        for (int i = 0; i < 4; ++i)
#pragma unroll
            for (int j = 0; j < 4; ++j)
#pragma unroll
                for (int r = 0; r < 4; ++r)
                    fb[(i * 16 + quad * 4 + r) * 64 + j * 16 + lrow] = acc[i][j][r];
    }
    __syncthreads();
    if (wv >= 2) {
        float* fb = (wv == 3) ? f1 : f0;
#pragma unroll
        for (int i = 0; i < 4; ++i)
#pragma unroll
            for (int j = 0; j < 4; ++j)
#pragma unroll
                for (int r = 0; r < 4; ++r)
                    fb[(i * 16 + quad * 4 + r) * 64 + j * 16 + lrow] += acc[i][j][r];
    }
    __syncthreads();
#pragma unroll
    for (int e = 0; e < 16; ++e) {
        int idx = e * 256 + tid;
        int row = idx >> 6, col = idx & 63;
        C[((size_t)blockIdx.x * 64 + row) * N + blockIdx.y * 64 + col] =
            f2bu(f0[idx] + f1[idx]);
    }
}

// ---------------------------------------------------------------------------
__global__ __launch_bounds__(256) void softmax_rows(unsigned short* __restrict__ S) {
    __shared__ float red[8];
    const int tid = threadIdx.x;
    const int wv = tid >> 6, lane = tid & 63;
    unsigned short* p = S + (size_t)blockIdx.x * 4096 + tid * 16;

    uint4 r0 = *reinterpret_cast<const uint4*>(p);
    uint4 r1 = *reinterpret_cast<const uint4*>(p + 8);
    unsigned w[8] = {r0.x, r0.y, r0.z, r0.w, r1.x, r1.y, r1.z, r1.w};
    float v[16];
#pragma unroll
    for (int q2 = 0; q2 < 8; ++q2) {
        v[q2 * 2 + 0] = b2f((unsigned short)(w[q2] & 0xffffu));
        v[q2 * 2 + 1] = b2f((unsigned short)(w[q2] >> 16));
    }
    float m = -3.0e38f;
#pragma unroll
    for (int q2 = 0; q2 < 16; ++q2) m = fmaxf(m, v[q2]);
#pragma unroll
    for (int o = 32; o; o >>= 1) m = fmaxf(m, __shfl_xor(m, o, 64));
    if (lane == 0) red[wv] = m;
    __syncthreads();
    m = fmaxf(fmaxf(red[0], red[1]), fmaxf(red[2], red[3]));

    float s = 0.f;
#pragma unroll
    for (int q2 = 0; q2 < 16; ++q2) { v[q2] = __expf(v[q2] - m); s += v[q2]; }
#pragma unroll
    for (int o = 32; o; o >>= 1) s += __shfl_xor(s, o, 64);
    if (lane == 0) red[4 + wv] = s;
    __syncthreads();
    s = red[4] + red[5] + red[6] + red[7];
    const float inv = 1.f / s;

    unsigned ow[8];
#pragma unroll
    for (int q2 = 0; q2 < 8; ++q2) {
        unsigned lo = f2bu(v[q2 * 2 + 0] * inv);
        unsigned hi = f2bu(v[q2 * 2 + 1] * inv);
        ow[q2] = lo | (hi << 16);
    }
    uint4 o0 = {ow[0], ow[1], ow[2], ow[3]};
    uint4 o1 = {ow[4], ow[5], ow[6], ow[7]};
    *reinterpret_cast<uint4*>(p) = o0;
    *reinterpret_cast<uint4*>(p + 8) = o1;
}

__global__ void write_sentinel_f32(float* out, float code) {
    if (threadIdx.x == 0) out[0] = code;
}

// ---------------------------------------------------------------------------
extern "C" void kernel_launch(void* const* d_in, const int* in_sizes, int n_in,
                              void* d_out, int out_size, void* d_ws, size_t ws_size,
                              hipStream_t stream) {
    const float* x   = (const float*)d_in[0];
    const float* gnw = (const float*)d_in[1];
    const float* gnb = (const float*)d_in[2];
    const float* wq  = (const float*)d_in[3];
    const float* bq  = (const float*)d_in[4];
    const float* wk  = (const float*)d_in[5];
    const float* bk  = (const float*)d_in[6];
    const float* wv  = (const float*)d_in[7];
    const float* bv  = (const float*)d_in[8];
    const float* wo  = (const float*)d_in[9];
    const float* bo  = (const float*)d_in[10];
    float* out = (float*)d_out;

    bool shapes_ok = (n_in == 11 && in_sizes[0] == 4194304 && in_sizes[1] == 512 &&
                      in_sizes[3] == 262144 && out_size == 4194304);
    size_t half = ws_size / 2;
    if (!shapes_ok || half < (size_t)17831936 + 128 * 4096) {
        write_sentinel_f32<<<1, 64, 0, stream>>>(out, shapes_ok ? 8000.f : 9000.f);
        return;
    }

    unsigned short* ws = (unsigned short*)d_ws;
    unsigned short* t  = ws;
    unsigned short* q  = ws + 4194304;
    unsigned short* k  = ws + 8388608;
    unsigned short* vT = ws + 12582912;
    unsigned short* o  = t;                      // alias: t dead after qkv GEMM
    const float scale = 0.044194173824159216f;   // 512^-0.5

    // weight/bias bf16 copies: wq|wk|wv contiguous (gemm_qkv needs that).
    unsigned short* wB0 = ws + 16777216;         // 3 x 262144 contiguous
    unsigned short* wB3 = ws + 17563648;         // wo
    unsigned short* bB0 = ws + 17825792;         // 3 x 512 contiguous
    unsigned short* bB3 = ws + 17827328;         // bo
    float* stats = (float*)(ws + 17827840);

    cast_f32_bf16<<<128, 256, 0, stream>>>(wq, wB0,          262144);
    cast_f32_bf16<<<128, 256, 0, stream>>>(wk, wB0 + 262144, 262144);
    cast_f32_bf16<<<128, 256, 0, stream>>>(wv, wB0 + 524288, 262144);
    cast_f32_bf16<<<1, 256, 0, stream>>>(bq, bB0,        512);
    cast_f32_bf16<<<1, 256, 0, stream>>>(bk, bB0 + 512,  512);
    cast_f32_bf16<<<1, 256, 0, stream>>>(bv, bB0 + 1024, 512);

    gn_stats<<<64, 256, 0, stream>>>(x, stats);
    build_t<<<dim3(64, 8, 2), 256, 0, stream>>>(x, stats, gnw, gnb, t);
    gemm_qkv<<<dim3(64, 12), 256, 0, stream>>>(t, wB0, bB0, q, k, vT);

    if (half >= (size_t)33554432) {
        // full per-batch S aliased over the (now dead) wq/wk/wv copies
        unsigned short* S = ws + 16777216;
        for (int b = 0; b < 2; ++b) {
            const unsigned short* qb  = q  + (size_t)b * 2097152;
            const unsigned short* kb  = k  + (size_t)b * 2097152;
            const unsigned short* vTb = vT + (size_t)b * 2097152;
            unsigned short*       ob  = o  + (size_t)b * 2097152;
            gemm_bt<2><<<dim3(32, 32), 256, 0, stream>>>(qb, kb, nullptr, nullptr, S, nullptr,
                                                         4096, 4096, 512, scale);
            softmax_rows<<<4096, 256, 0, stream>>>(S);
            ksplit_o<<<dim3(64, 8), 256, 0, stream>>>(S, vTb, ob, 512, 4096);
        }
    } else {
        // chunked fallback (S after the weight copies)
        unsigned short* S = ws + 17831936;
        size_t avail = half - 17831936;
        int R = 4096;
        while (R > 128 && (size_t)R * 4096 > avail) R >>= 1;
        for (int b = 0; b < 2; ++b) {
            const unsigned short* qb  = q  + (size_t)b * 2097152;
            const unsigned short* kb  = k  + (size_t)b * 2097152;
            const unsigned short* vTb = vT + (size_t)b * 2097152;
            unsigned short*       ob  = o  + (size_t)b * 2097152;
            for (int r0 = 0; r0 < 4096; r0 += R) {
                gemm_bt<2><<<dim3(R / 128, 32), 256, 0, stream>>>(
                    qb + (size_t)r0 * 512, kb, nullptr, nullptr, S, nullptr, R, 4096, 512, scale);
                softmax_rows<<<R, 256, 0, stream>>>(S);
                ksplit_o<<<dim3(R / 64, 8), 256, 0, stream>>>(
                    S, vTb, ob + (size_t)r0 * 512, 512, 4096);
            }
        }
    }
    // final projection (wo/bo cast after S is dead; region inside S span)
    cast_f32_bf16<<<128, 256, 0, stream>>>(wo, wB3, 262144);
    cast_f32_bf16<<<1, 256, 0, stream>>>(bo, bB3, 512);
    gemm_bt<3><<<dim3(64, 4), 256, 0, stream>>>(o, wB3, bB3, x, nullptr, out,
                                                8192, 512, 512, 1.f);
}